// Round 5
// baseline (320.175 us; speedup 1.0000x reference)
//
#include <hip/hip_runtime.h>
#include <hip/hip_bf16.h>
#include <hip/hip_cooperative_groups.h>

namespace cg = cooperative_groups;

// SubClusteringNet: N=131072, K=16, IN=256, OUT=128
#define KEXP   16
#define IN_DIM 256
#define OUT_DIM 128
#define TILE   128        // tokens per tile
#define BPE    16         // persistent blocks per expert
#define NBLK   256        // 1 block / CU
#define NTHR   512        // 8 waves

typedef float f32x4 __attribute__((ext_vector_type(4)));
typedef short bf16x8 __attribute__((ext_vector_type(8)));
typedef const unsigned int __attribute__((address_space(1)))* gptr_t;
typedef unsigned int __attribute__((address_space(3)))* lptr_t;

__device__ __forceinline__ ushort f2bf(float f) {
    union { float f; unsigned u; } v; v.f = f;
    return (ushort)((v.u + 0x7fffu + ((v.u >> 16) & 1u)) >> 16);  // RNE
}

// One cooperative kernel: [histogram + W1-transpose] gsync [scan] gsync [scatter]
// gsync [persistent grouped GEMM + head + softmax].
__global__ __launch_bounds__(NTHR, 1) void fused_k(
    const float* __restrict__ x, const int* __restrict__ z,
    const float* __restrict__ W1, const float* __restrict__ b1,
    const float* __restrict__ W2, const float* __restrict__ b2,
    float* __restrict__ out,
    int* __restrict__ counts, int* __restrict__ cursors,
    int* __restrict__ bases, int* __restrict__ perm,
    ushort* __restrict__ w1t, int n) {
    __shared__ __align__(16) char smem[131072];
    cg::grid_group grid = cg::this_grid();
    int bid = blockIdx.x, tid = threadIdx.x;

    // ---------------- Phase A: W1 transpose->bf16 pre-swizzled (blocks<128, thr 0-255)
    // ----------------           + z histogram (all blocks, thr 256-511, 2 tok/thr)
    {
        float (*ld)[65] = (float(*)[65])smem;                  // 16.6 KB
        int* shh = (int*)(smem + 73728);
        if (tid < KEXP) shh[tid] = 0;
        __syncthreads();
        int e = bid >> 3, sub = bid & 7;
        int k0 = (sub & 3) * 64, n0 = (sub >> 2) * 64;
        int tr = tid >> 6, tc = tid & 63;
        if (bid < 128 && tid < 256) {
            const float* src = W1 + (long)e * (IN_DIM * OUT_DIM);   // [256][128]
#pragma unroll
            for (int i = 0; i < 16; i++)
                ld[i * 4 + tr][tc] = src[(k0 + i * 4 + tr) * OUT_DIM + n0 + tc];
        }
        if (tid >= 256) {
            int t0 = bid * 512 + (tid - 256);
            if (t0 < n)       atomicAdd(&shh[z[t0]], 1);
            if (t0 + 256 < n) atomicAdd(&shh[z[t0 + 256]], 1);
        }
        __syncthreads();
        if (bid < 128 && tid < 256) {
            char* dst = (char*)w1t + (long)e * (OUT_DIM * IN_DIM * 2);
#pragma unroll
            for (int i = 0; i < 16; i++) {
                int col = n0 + i * 4 + tr;                      // out col
                int L = (col * IN_DIM + k0 + tc) * 2;           // logical byte
                *(ushort*)(dst + (L ^ ((col & 7) << 4))) = f2bf(ld[tc][i * 4 + tr]);
            }
        }
        if (tid < KEXP) atomicAdd(&counts[tid], shh[tid]);
    }
    grid.sync();

    // ---------------- Phase B: exclusive scan (block 0, wave 0) ----------------
    if (bid == 0 && tid < 64) {
        int c = (tid < KEXP) ? counts[tid] : 0;
        int v = c;
#pragma unroll
        for (int d = 1; d < KEXP; d <<= 1) {
            int t = __shfl_up(v, d, 64);
            if (tid >= d) v += t;
        }
        if (tid < KEXP) bases[tid] = v - c;
    }
    grid.sync();

    // ---------------- Phase C: scatter perm (1 token/thread) ----------------
    {
        int* lc = (int*)smem;
        int* lb = lc + 16;
        if (tid < KEXP) lc[tid] = 0;
        __syncthreads();
        int i = bid * 512 + tid;
        int e = -1, r = 0;
        if (i < n) {
            e = z[i];
            r = atomicAdd(&lc[e], 1);
        }
        __syncthreads();
        if (tid < KEXP && lc[tid] > 0) lb[tid] = atomicAdd(&cursors[tid], lc[tid]);
        __syncthreads();
        if (e >= 0) perm[bases[e] + lb[e] + r] = i;
    }
    grid.sync();

    // ---------------- Phase D: persistent grouped GEMM + head + softmax ----------------
    // Block b: expert b>>4, tile slots (b&15)+16j. LDS: W 64KB (staged once via linear
    // global_load_lds from pre-swizzled w1t) + A 64KB. perm for tile t+1 prefetched
    // before the barrier; its x-row loads issue right after and hide under compute.
    {
        char* Wl = smem;
        char* Al = smem + 65536;
        int b = bid;
        int e = b >> 4, slot = b & 15;
        int cnt = counts[e];
        int pb0 = bases[e];
        int ntiles = (cnt + TILE - 1) / TILE;

        int lane = tid & 63, w = tid >> 6;
        int li = lane & 15, q = lane >> 4;

        // stage W (64 KB) once: 8 x 1KB linear global_load_lds per wave
        const char* wsrc = (const char*)w1t + (long)e * (OUT_DIM * IN_DIM * 2);
#pragma unroll
        for (int i = 0; i < 8; i++) {
            int off = w * 8192 + i * 1024;
            __builtin_amdgcn_global_load_lds((gptr_t)(wsrc + off + lane * 16),
                                             (lptr_t)(Wl + off), 16, 0, 0);
        }

        // hoist epilogue constants (expert-fixed)
        float bbv[8], w2a[8], w2b[8];
#pragma unroll
        for (int nn = 0; nn < 8; nn++) {
            int col = nn * 16 + li;
            bbv[nn] = b1[e * OUT_DIM + col];
            w2a[nn] = W2[(e * OUT_DIM + col) * 2 + 0];
            w2b[nn] = W2[(e * OUT_DIM + col) * 2 + 1];
        }
        float bb0 = b2[e * 2 + 0], bb1 = b2[e * 2 + 1];

        // prologue: load + pack first tile
        uint2 pk[16];
        int pb_cur = 0, nr_cur = 0;
        if (slot < ntiles) {
            pb_cur = pb0 + slot * TILE;
            nr_cur = cnt - slot * TILE;
            int rr = w * 16 + li;
            int pv = perm[pb_cur + (rr < nr_cur ? rr : nr_cur - 1)];
            f32x4 av[16];
#pragma unroll
            for (int i = 0; i < 16; i++) {
                int g = __shfl(pv, i, 16);
                av[i] = *(const f32x4*)((const char*)x + (long)g * 1024 + lane * 16);
            }
#pragma unroll
            for (int i = 0; i < 16; i++) {
                pk[i].x = (unsigned)f2bf(av[i][0]) | ((unsigned)f2bf(av[i][1]) << 16);
                pk[i].y = (unsigned)f2bf(av[i][2]) | ((unsigned)f2bf(av[i][3]) << 16);
            }
        }

        for (int t = slot; t < ntiles; t += BPE) {
            // prefetch next tile's perm row-index (hides perm latency behind ds_write+sync)
            int tn = t + BPE;
            bool have_nx = (tn < ntiles);
            int pb_nx = 0, nr_nx = 0, pv_nx = 0;
            if (have_nx) {
                pb_nx = pb0 + tn * TILE;
                nr_nx = cnt - tn * TILE;
                int rr = w * 16 + li;
                pv_nx = perm[pb_nx + (rr < nr_nx ? rr : nr_nx - 1)];
            }

            // swizzled ds_write of current A tile
#pragma unroll
            for (int i = 0; i < 16; i++) {
                int r = w * 16 + i;
                *(uint2*)(Al + r * 512 + ((lane * 8) ^ ((r & 7) << 4))) = pk[i];
            }
            __syncthreads();   // A (and W on first iter) visible to all waves

            // issue NEXT tile's x-row loads (consumed after compute)
            f32x4 av[16];
            if (have_nx) {
#pragma unroll
                for (int i = 0; i < 16; i++) {
                    int g = __shfl(pv_nx, i, 16);
                    av[i] = *(const f32x4*)((const char*)x + (long)g * 1024 + lane * 16);
                }
            }

            // compute: wave w = m-tile w (16 tokens) x 128 cols; 8 kk x 8 nn MFMA
            f32x4 acc[8];
#pragma unroll
            for (int nn = 0; nn < 8; nn++) acc[nn] = (f32x4)0.0f;
            int arow = w * 16 + li;
            int aswz = (arow & 7) << 4;
#pragma unroll
            for (int kk = 0; kk < 8; kk++) {
                bf16x8 af = *(const bf16x8*)(Al + arow * 512 + ((kk * 64 + q * 16) ^ aswz));
#pragma unroll
                for (int nn = 0; nn < 8; nn++) {
                    int col = nn * 16 + li;
                    bf16x8 bf = *(const bf16x8*)(Wl + col * 512 + ((kk * 64 + q * 16) ^ ((col & 7) << 4)));
                    acc[nn] = __builtin_amdgcn_mfma_f32_16x16x32_bf16(af, bf, acc[nn], 0, 0, 0);
                }
            }

            // epilogue: relu + 128->2 head + softmax; 16-lane butterfly over li
            float p0[4] = {0.f, 0.f, 0.f, 0.f}, p1[4] = {0.f, 0.f, 0.f, 0.f};
#pragma unroll
            for (int nn = 0; nn < 8; nn++) {
#pragma unroll
                for (int r = 0; r < 4; r++) {
                    float h = fmaxf(acc[nn][r] + bbv[nn], 0.0f);
                    p0[r] += h * w2a[nn];
                    p1[r] += h * w2b[nn];
                }
            }
#pragma unroll
            for (int m = 1; m < 16; m <<= 1)
#pragma unroll
                for (int r = 0; r < 4; r++) {
                    p0[r] += __shfl_xor(p0[r], m, 64);
                    p1[r] += __shfl_xor(p1[r], m, 64);
                }
            if (li == 0) {
#pragma unroll
                for (int r = 0; r < 4; r++) {
                    int mm = w * 16 + q * 4 + r;
                    if (mm < nr_cur) {
                        int orig = perm[pb_cur + mm];
                        float l0 = p0[r] + bb0, l1 = p1[r] + bb1;
                        float mx = fmaxf(l0, l1);
                        float e0 = __expf(l0 - mx), e1 = __expf(l1 - mx);
                        float inv = 1.0f / (e0 + e1);
                        *(float2*)(out + (long)orig * 2) = make_float2(e0 * inv, e1 * inv);
                    }
                }
            }

            // convert next tile to bf16 (loads have arrived during compute)
            if (have_nx) {
#pragma unroll
                for (int i = 0; i < 16; i++) {
                    pk[i].x = (unsigned)f2bf(av[i][0]) | ((unsigned)f2bf(av[i][1]) << 16);
                    pk[i].y = (unsigned)f2bf(av[i][2]) | ((unsigned)f2bf(av[i][3]) << 16);
                }
            }
            __syncthreads();   // all reads of Al done before overwrite
            pb_cur = pb_nx;
            nr_cur = nr_nx;
        }
    }
}

extern "C" void kernel_launch(void* const* d_in, const int* in_sizes, int n_in,
                              void* d_out, int out_size, void* d_ws, size_t ws_size,
                              hipStream_t stream) {
    const float* x  = (const float*)d_in[0];
    const int*   z  = (const int*)d_in[1];
    const float* W1 = (const float*)d_in[2];
    const float* b1 = (const float*)d_in[3];
    const float* W2 = (const float*)d_in[4];
    const float* b2 = (const float*)d_in[5];
    float* out = (float*)d_out;
    int n = in_sizes[1];                    // 131072 tokens

    // ws layout: [counts 16][cursors 16][bases 16][pad] perm[n] @1024 ... w1t bf16
    int* counts  = (int*)d_ws;
    int* cursors = counts + 16;
    int* basesp  = counts + 32;
    int* perm    = counts + 256;                                  // byte offset 1024
    ushort* w1t  = (ushort*)((char*)d_ws + 1024 + (size_t)n * 4); // 16B-aligned

    hipMemsetAsync(counts, 0, 128, stream);                       // counts + cursors

    void* args[] = {(void*)&x, (void*)&z, (void*)&W1, (void*)&b1, (void*)&W2,
                    (void*)&b2, (void*)&out, (void*)&counts, (void*)&cursors,
                    (void*)&basesp, (void*)&perm, (void*)&w1t, (void*)&n};
    hipLaunchCooperativeKernel((void*)fused_k, dim3(NBLK), dim3(NTHR), args, 0, stream);
}